// Round 1
// baseline (178.178 us; speedup 1.0000x reference)
//
#include <hip/hip_runtime.h>

// Weighted Chamfer, B=4, N=M=8192, D=3, fp32 in/out.
// out = (1/B)*[ sum_b sum_n w*min_m d2 + sum_b sum_m min_n d2 ]
//
// One v_mfma_f32_32x32x16_bf16 yields a 32x32 tile of d2 = s2 + t2 - 2 s.t
// via K-slot packing with split-bf16 compensation (verified r2-r17):
//   A(plain)  half0 {hx,hx,lx,hy,hy,ly,hz,hz} half1 {lz,h2,l2,1,1,0,0,0}
//   B(-2 scl) half0 {nhx,nlx,nhx,nhy,nly,nhy,nhz,nlz} half1 {nhz,1,1,h2,l2,0,0,0}
//   Error ~1e-5 (threshold 5.76). C/D layout: col=lane&31.
// Transposed operands (r8): DB = A staged in LDS, queries = B in registers ->
// per-lane scalar running min. i32-domain min (r13) folds to v_min3_i32.
// Self-packing (r14): no prep kernel; -2*bf16 in int bits ((h^0x8000)+0x80).
// Fence rule (r18): fused finishers falsified; separate reduce launch.
//
// Round 20 theory: r11 counters (MfmaUtil 44 + VALUBusy 52 = 96%) show the
// pipes running ADDITIVELY, not overlapped. Per-SIMD floors: MFMA 16.4k cyc
// (6.8 us), VALU ~13k cyc (min3 8.2k irreducible + packing). Scan ~22 us =
// sum-of-pipes + stalls; overlapped target ~8 us. Changes:
//  (a) modulo-scheduled inner loop: mfma pair for rf+1 issued BEFORE the
//      min3 chain of rf consumes its results (named ping-pong f32x16 regs,
//      static indices). Steady-state beat {2 mfma, 16 min3} balances
//      matrix (64 cyc) vs VALU (32 cyc) per wave.
//  (b) WAVES=8 blocks (512 thr, grid 512, still 4 waves/SIMD): halves the
//      DB staging redundancy (8 query-blocks per chunk instead of 16).
//  (c) float2-vectorized staging loads (3 x dwordx2 per 2 points).

typedef short bf16x8 __attribute__((ext_vector_type(8)));
typedef float f32x16 __attribute__((ext_vector_type(16)));

#define BB 4
#define NP 8192
#define RF 4                     // query-frags per wave (128 queries)
#define WAVES 8                  // 512 threads; 1024 queries per block
#define QBLOCKS 8                // 8192 / 1024
#define CFRAGS 32                // DB frags per LDS stage (1024 pts, 32 KB)
#define NCHG 8                   // DB chunks (8192 / 1024)

__device__ __forceinline__ int smin3(int a, int b, int c) {
    int m = a < b ? a : b;
    return (m < c) ? m : c;      // folds to v_min3_i32
}
__device__ __forceinline__ unsigned short bf16r(float x) {
    unsigned u = __float_as_uint(x);
    unsigned r = u + 0x7FFFu + ((u >> 16) & 1u);
    return (unsigned short)(r >> 16);
}
__device__ __forceinline__ float bf16f(unsigned short h) {
    return __uint_as_float(((unsigned)h) << 16);
}
// -2 * bf16(h), exact in bits (sign flip + exponent+1); h==+-0 -> tiny
// denormal ~1e-38 whose products are << 1e-5 packing error.
__device__ __forceinline__ unsigned short neg2(unsigned short h) {
    return (unsigned short)((h ^ 0x8000u) + 0x0080u);
}

struct Pack {
    unsigned short hx, lx, hy, ly, hz, lz, h2, l2;
};
__device__ __forceinline__ Pack mkpack(float x, float y, float z) {
    Pack p;
    p.hx = bf16r(x); p.lx = bf16r(x - bf16f(p.hx));
    p.hy = bf16r(y); p.ly = bf16r(y - bf16f(p.hy));
    p.hz = bf16r(z); p.lz = bf16r(z - bf16f(p.hz));
    float n2 = x * x + y * y + z * z;
    p.h2 = bf16r(n2); p.l2 = bf16r(n2 - bf16f(p.h2));
    return p;
}

#define ONE 0x3F80u

__device__ __forceinline__ void stash(uint4* ash, int i, const Pack& p) {
    uint4 h0, h1;
    h0.x = (unsigned)p.hx | ((unsigned)p.hx << 16);
    h0.y = (unsigned)p.lx | ((unsigned)p.hy << 16);
    h0.z = (unsigned)p.hy | ((unsigned)p.ly << 16);
    h0.w = (unsigned)p.hz | ((unsigned)p.hz << 16);
    h1.x = (unsigned)p.lz | ((unsigned)p.h2 << 16);
    h1.y = (unsigned)p.l2 | (ONE << 16);
    h1.z = ONE;
    h1.w = 0u;
    int f = i >> 5, m = i & 31;
    ash[f * 64 + m]      = h0;
    ash[f * 64 + 32 + m] = h1;
}

// ---- scan: self-packing; DB rows from LDS, queries in regs, i32 min3 ----
__global__ __launch_bounds__(512, 4) void scan_kernel(
    const float* __restrict__ src, const float* __restrict__ tgt,
    float* __restrict__ part,   // part[dir][b][ch][query]
    float* __restrict__ out)
{
    __shared__ uint4 ash[CFRAGS * 64];          // 32 KB DB stage (A-packs)
    const int tid = threadIdx.x;
    const int lane = tid & 63, wave = tid >> 6;
    const int qb = blockIdx.x, b = blockIdx.y;
    const int dir = blockIdx.z >> 3, ch = blockIdx.z & (NCHG - 1);

    if (blockIdx.x == 0 && blockIdx.y == 0 && blockIdx.z == 0 && tid == 0)
        out[0] = 0.0f;

    // dir 0: queries = source, DB = target; dir 1 mirrored.
    const float* dbc = (dir ? src : tgt) + ((size_t)b * NP + ch * 1024) * 3;
    const float* qc  = (dir ? tgt : src) + ((size_t)b * NP + qb * (WAVES * RF * 32)) * 3;

    // ---- stage DB chunk: 2 points/thread via 3x float2 loads ----
    {
        const float2* db2 = (const float2*)dbc;      // 8B-aligned (12KB offs)
        float2 v0 = db2[tid * 3 + 0];
        float2 v1 = db2[tid * 3 + 1];
        float2 v2 = db2[tid * 3 + 2];
        Pack pa = mkpack(v0.x, v0.y, v1.x);
        Pack pb = mkpack(v1.y, v2.x, v2.y);
        stash(ash, tid * 2 + 0, pa);
        stash(ash, tid * 2 + 1, pb);
    }

    // ---- pack this lane's query B-frags in registers ----
    const int half = lane >> 5, m = lane & 31;
    bf16x8 qfrag[RF];
#pragma unroll
    for (int rf = 0; rf < RF; rf++) {
        int q = wave * (RF * 32) + rf * 32 + m;
        float x = qc[q * 3 + 0], y = qc[q * 3 + 1], z = qc[q * 3 + 2];
        Pack p = mkpack(x, y, z);
        unsigned short nhx = neg2(p.hx), nlx = neg2(p.lx);
        unsigned short nhy = neg2(p.hy), nly = neg2(p.ly);
        unsigned short nhz = neg2(p.hz), nlz = neg2(p.lz);
        uint4 v;
        if (half == 0) {
            v.x = (unsigned)nhx | ((unsigned)nlx << 16);
            v.y = (unsigned)nhx | ((unsigned)nhy << 16);
            v.z = (unsigned)nly | ((unsigned)nhy << 16);
            v.w = (unsigned)nhz | ((unsigned)nlz << 16);
        } else {
            v.x = (unsigned)nhz | (ONE << 16);
            v.y = ONE | ((unsigned)p.h2 << 16);
            v.z = (unsigned)p.l2;
            v.w = 0u;
        }
        qfrag[rf] = *(bf16x8*)&v;
    }

    int vmini[RF];
#pragma unroll
    for (int rf = 0; rf < RF; rf++) vmini[rf] = __float_as_int(1e30f);
    f32x16 zero = {};
    __syncthreads();                            // the block's only barrier

    // ---- modulo-scheduled main loop: mfma pair rf+1 in flight while the
    //      min3 chain consumes rf; ds_read for t+2 rotated into the slot
    //      after the last use of a0/a1 (reuses the same registers). ----
    bf16x8 a0 = *(bf16x8*)&ash[lane];
    bf16x8 a1 = *(bf16x8*)&ash[64 + lane];
    for (int t = 0; t < CFRAGS; t += 2) {
        f32x16 rA0 = __builtin_amdgcn_mfma_f32_32x32x16_bf16(a0, qfrag[0], zero, 0, 0, 0);
        f32x16 rB0 = __builtin_amdgcn_mfma_f32_32x32x16_bf16(a1, qfrag[0], zero, 0, 0, 0);
        f32x16 rA1 = __builtin_amdgcn_mfma_f32_32x32x16_bf16(a0, qfrag[1], zero, 0, 0, 0);
        f32x16 rB1 = __builtin_amdgcn_mfma_f32_32x32x16_bf16(a1, qfrag[1], zero, 0, 0, 0);
#pragma unroll
        for (int i = 0; i < 16; i++)
            vmini[0] = smin3(__float_as_int(rA0[i]), __float_as_int(rB0[i]), vmini[0]);
        rA0 = __builtin_amdgcn_mfma_f32_32x32x16_bf16(a0, qfrag[2], zero, 0, 0, 0);
        rB0 = __builtin_amdgcn_mfma_f32_32x32x16_bf16(a1, qfrag[2], zero, 0, 0, 0);
#pragma unroll
        for (int i = 0; i < 16; i++)
            vmini[1] = smin3(__float_as_int(rA1[i]), __float_as_int(rB1[i]), vmini[1]);
        rA1 = __builtin_amdgcn_mfma_f32_32x32x16_bf16(a0, qfrag[3], zero, 0, 0, 0);
        rB1 = __builtin_amdgcn_mfma_f32_32x32x16_bf16(a1, qfrag[3], zero, 0, 0, 0);
        if (t + 2 < CFRAGS) {                   // a0/a1 dead: prefetch t+2
            a0 = *(bf16x8*)&ash[(t + 2) * 64 + lane];
            a1 = *(bf16x8*)&ash[(t + 3) * 64 + lane];
        }
#pragma unroll
        for (int i = 0; i < 16; i++)
            vmini[2] = smin3(__float_as_int(rA0[i]), __float_as_int(rB0[i]), vmini[2]);
#pragma unroll
        for (int i = 0; i < 16; i++)
            vmini[3] = smin3(__float_as_int(rA1[i]), __float_as_int(rB1[i]), vmini[3]);
    }

    // finalize: lane^32 holds the other 16 DB rows of the same query column
    float* pbase = part + ((size_t)(dir * BB + b) * NCHG + ch) * NP
                 + qb * (WAVES * RF * 32) + wave * (RF * 32);
#pragma unroll
    for (int rf = 0; rf < RF; rf++) {
        float v = __int_as_float(vmini[rf]);
        v = fminf(v, __shfl_xor(v, 32, 64));
        if (lane < 32) pbase[rf * 32 + lane] = v;
    }
}

// ---- reduce: min over DB chunks, weight, sum, atomicAdd ----
__global__ __launch_bounds__(256) void reduce_kernel(
    const float* __restrict__ weights, const float* __restrict__ part,
    float* __restrict__ out)
{
    int tid = threadIdx.x;
    int gid = blockIdx.x * 256 + tid;       // 0 .. 65535
    int dir = gid >> 15;
    int r   = gid & 32767;
    int b   = r >> 13;
    int q   = r & (NP - 1);

    const float* p = part + ((size_t)(dir * BB + b) * NCHG) * NP + q;
    float mn = 1e30f;
#pragma unroll
    for (int i = 0; i < NCHG; i++) mn = fminf(mn, p[(size_t)i * NP]);
    float w = dir ? 1.0f : weights[b * NP + q];
    float v = mn * w * (1.0f / BB);
#pragma unroll
    for (int off = 32; off; off >>= 1) v += __shfl_down(v, off, 64);
    __shared__ float ls[4];
    if ((tid & 63) == 0) ls[tid >> 6] = v;
    __syncthreads();
    if (tid == 0) atomicAdd(out, ls[0] + ls[1] + ls[2] + ls[3]);
}

extern "C" void kernel_launch(void* const* d_in, const int* in_sizes, int n_in,
                              void* d_out, int out_size, void* d_ws, size_t ws_size,
                              hipStream_t stream) {
    const float* src = (const float*)d_in[0];   // (B, N, 3)
    const float* tgt = (const float*)d_in[1];   // (B, M, 3)
    const float* wgt = (const float*)d_in[2];   // (B, N)
    float* out = (float*)d_out;

    float* part = (float*)d_ws;                 // 2 MB: [2][BB][NCHG][NP]

    scan_kernel<<<dim3(QBLOCKS, BB, 2 * NCHG), dim3(512), 0, stream>>>(
        src, tgt, part, out);
    reduce_kernel<<<dim3(256), dim3(256), 0, stream>>>(wgt, part, out);
}

// Round 2
// 174.848 us; speedup vs baseline: 1.0190x; 1.0190x over previous
//
#include <hip/hip_runtime.h>

// Weighted Chamfer, B=4, N=M=8192, D=3, fp32 in/out.
// out = (1/B)*[ sum_b sum_n w*min_m d2 + sum_b sum_m min_n d2 ]
//
// One v_mfma_f32_32x32x16_bf16 yields a 32x32 tile of d2 = s2 + t2 - 2 s.t
// via K-slot packing with split-bf16 compensation (verified r2-r17):
//   A(plain)  half0 {hx,hx,lx,hy,hy,ly,hz,hz} half1 {lz,h2,l2,1,1,0,0,0}
//   B(-2 scl) half0 {nhx,nlx,nhx,nhy,nly,nhy,nhz,nlz} half1 {nhz,1,1,h2,l2,0,0,0}
//   Error ~1e-5 (threshold 5.76). C/D layout: col=lane&31.
// Transposed operands (r8): DB = A staged in LDS, queries = B in registers ->
// per-lane scalar running min. i32-domain min (r13) folds to v_min3_i32.
// Self-packing (r14): no prep kernel; -2*bf16 in int bits ((h^0x8000)+0x80).
// Reg rule (r16, re-confirmed r20): body needs >= ~100-reg budget;
// launch_bounds(256,4) ONLY. r20's (512,4) made the compiler budget 64 VGPRs
// -> all f32x16 results spilled (WRITE_SIZE 335 MB/dispatch, scan 127 us).
// Fence rule (r18): fused finishers falsified; separate reduce launch.
//
// Round 21: r19 config restored exactly (256 thr, launch_bounds(256,4),
// QBLOCKS=16, scalar staging); ONE change vs r19 — the inner loop is
// software-pipelined with a 3-buffer rotation (X,Y,Z f32x16 = 48 result
// VGPRs, vs 64 in the failed r20 4-buffer version): every 16-min3 chain
// runs with the next mfma pair already issued, so the matrix pipe stays
// fed during VALU beats instead of the pipes running additively
// (r11: MfmaUtil 44 + VALUBusy 52 = 96% additive).

typedef short bf16x8 __attribute__((ext_vector_type(8)));
typedef float f32x16 __attribute__((ext_vector_type(16)));

#define BB 4
#define NP 8192
#define RF 4                     // query-frags per wave (128 queries)
#define WAVES 4                  // 256 threads; 512 queries per block
#define QBLOCKS 16               // 8192 / 512
#define CFRAGS 32                // DB frags per LDS stage (1024 pts, 32 KB)
#define NCHG 8                   // DB chunks (8192 / 1024)

__device__ __forceinline__ int smin3(int a, int b, int c) {
    int m = a < b ? a : b;
    return (m < c) ? m : c;      // folds to v_min3_i32
}
__device__ __forceinline__ unsigned short bf16r(float x) {
    unsigned u = __float_as_uint(x);
    unsigned r = u + 0x7FFFu + ((u >> 16) & 1u);
    return (unsigned short)(r >> 16);
}
__device__ __forceinline__ float bf16f(unsigned short h) {
    return __uint_as_float(((unsigned)h) << 16);
}
// -2 * bf16(h), exact in bits (sign flip + exponent+1); h==+-0 -> tiny
// denormal ~1e-38 whose products are << 1e-5 packing error.
__device__ __forceinline__ unsigned short neg2(unsigned short h) {
    return (unsigned short)((h ^ 0x8000u) + 0x0080u);
}

struct Pack {
    unsigned short hx, lx, hy, ly, hz, lz, h2, l2;
};
__device__ __forceinline__ Pack mkpack(float x, float y, float z) {
    Pack p;
    p.hx = bf16r(x); p.lx = bf16r(x - bf16f(p.hx));
    p.hy = bf16r(y); p.ly = bf16r(y - bf16f(p.hy));
    p.hz = bf16r(z); p.lz = bf16r(z - bf16f(p.hz));
    float n2 = x * x + y * y + z * z;
    p.h2 = bf16r(n2); p.l2 = bf16r(n2 - bf16f(p.h2));
    return p;
}

#define ONE 0x3F80u

// ---- scan: self-packing; DB rows from LDS, queries in regs, i32 min3 ----
__global__ __launch_bounds__(256, 4) void scan_kernel(
    const float* __restrict__ src, const float* __restrict__ tgt,
    float* __restrict__ part,   // part[dir][b][ch][query]
    float* __restrict__ out)
{
    __shared__ uint4 ash[CFRAGS * 64];          // 32 KB DB stage (A-packs)
    const int tid = threadIdx.x;
    const int lane = tid & 63, wave = tid >> 6;
    const int qb = blockIdx.x, b = blockIdx.y;
    const int dir = blockIdx.z >> 3, ch = blockIdx.z & (NCHG - 1);

    if (blockIdx.x == 0 && blockIdx.y == 0 && blockIdx.z == 0 && tid == 0)
        out[0] = 0.0f;

    // dir 0: queries = source, DB = target; dir 1 mirrored.
    const float* dbc = (dir ? src : tgt) + ((size_t)b * NP + ch * 1024) * 3;
    const float* qc  = (dir ? tgt : src) + ((size_t)b * NP + qb * (WAVES * RF * 32)) * 3;

    // ---- stage DB chunk: 4 points/thread, pack A-layout into LDS ----
#pragma unroll
    for (int j = 0; j < 4; j++) {
        int i = tid + j * 256;
        float x = dbc[i * 3 + 0], y = dbc[i * 3 + 1], z = dbc[i * 3 + 2];
        Pack p = mkpack(x, y, z);
        uint4 h0, h1;
        h0.x = (unsigned)p.hx | ((unsigned)p.hx << 16);
        h0.y = (unsigned)p.lx | ((unsigned)p.hy << 16);
        h0.z = (unsigned)p.hy | ((unsigned)p.ly << 16);
        h0.w = (unsigned)p.hz | ((unsigned)p.hz << 16);
        h1.x = (unsigned)p.lz | ((unsigned)p.h2 << 16);
        h1.y = (unsigned)p.l2 | (ONE << 16);
        h1.z = ONE;
        h1.w = 0u;
        int f = i >> 5, m = i & 31;
        ash[f * 64 + m]      = h0;
        ash[f * 64 + 32 + m] = h1;
    }

    // ---- pack this lane's query B-frags in registers ----
    const int half = lane >> 5, m = lane & 31;
    bf16x8 qfrag[RF];
#pragma unroll
    for (int rf = 0; rf < RF; rf++) {
        int q = wave * (RF * 32) + rf * 32 + m;
        float x = qc[q * 3 + 0], y = qc[q * 3 + 1], z = qc[q * 3 + 2];
        Pack p = mkpack(x, y, z);
        unsigned short nhx = neg2(p.hx), nlx = neg2(p.lx);
        unsigned short nhy = neg2(p.hy), nly = neg2(p.ly);
        unsigned short nhz = neg2(p.hz), nlz = neg2(p.lz);
        uint4 v;
        if (half == 0) {
            v.x = (unsigned)nhx | ((unsigned)nlx << 16);
            v.y = (unsigned)nhx | ((unsigned)nhy << 16);
            v.z = (unsigned)nly | ((unsigned)nhy << 16);
            v.w = (unsigned)nhz | ((unsigned)nlz << 16);
        } else {
            v.x = (unsigned)nhz | (ONE << 16);
            v.y = ONE | ((unsigned)p.h2 << 16);
            v.z = (unsigned)p.l2;
            v.w = 0u;
        }
        qfrag[rf] = *(bf16x8*)&v;
    }

    int vmini[RF];
#pragma unroll
    for (int rf = 0; rf < RF; rf++) vmini[rf] = __float_as_int(1e30f);
    f32x16 zero = {};
    __syncthreads();                            // the block's only barrier

    // ---- 3-buffer modulo-scheduled main loop: each 16-min3 chain runs
    //      with the next mfma pair already issued. Pair for vmini[rf] is
    //      always (a0*q[rf], a1*q[rf]); buffers rotate X,Y,Z. ----
    bf16x8 a0 = *(bf16x8*)&ash[lane];
    bf16x8 a1 = *(bf16x8*)&ash[64 + lane];
    for (int t = 0; t < CFRAGS; t += 2) {
        f32x16 X = __builtin_amdgcn_mfma_f32_32x32x16_bf16(a0, qfrag[0], zero, 0, 0, 0);
        f32x16 Y = __builtin_amdgcn_mfma_f32_32x32x16_bf16(a1, qfrag[0], zero, 0, 0, 0);
        f32x16 Z = __builtin_amdgcn_mfma_f32_32x32x16_bf16(a0, qfrag[1], zero, 0, 0, 0);
#pragma unroll
        for (int i = 0; i < 16; i++)
            vmini[0] = smin3(__float_as_int(X[i]), __float_as_int(Y[i]), vmini[0]);
        X = __builtin_amdgcn_mfma_f32_32x32x16_bf16(a1, qfrag[1], zero, 0, 0, 0);
        Y = __builtin_amdgcn_mfma_f32_32x32x16_bf16(a0, qfrag[2], zero, 0, 0, 0);
#pragma unroll
        for (int i = 0; i < 16; i++)
            vmini[1] = smin3(__float_as_int(Z[i]), __float_as_int(X[i]), vmini[1]);
        Z = __builtin_amdgcn_mfma_f32_32x32x16_bf16(a1, qfrag[2], zero, 0, 0, 0);
        X = __builtin_amdgcn_mfma_f32_32x32x16_bf16(a0, qfrag[3], zero, 0, 0, 0);
#pragma unroll
        for (int i = 0; i < 16; i++)
            vmini[2] = smin3(__float_as_int(Y[i]), __float_as_int(Z[i]), vmini[2]);
        Y = __builtin_amdgcn_mfma_f32_32x32x16_bf16(a1, qfrag[3], zero, 0, 0, 0);
        if (t + 2 < CFRAGS) {                   // a0/a1 dead: prefetch t+2
            a0 = *(bf16x8*)&ash[(t + 2) * 64 + lane];
            a1 = *(bf16x8*)&ash[(t + 3) * 64 + lane];
        }
#pragma unroll
        for (int i = 0; i < 16; i++)
            vmini[3] = smin3(__float_as_int(X[i]), __float_as_int(Y[i]), vmini[3]);
    }

    // finalize: lane^32 holds the other 16 DB rows of the same query column
    float* pbase = part + ((size_t)(dir * BB + b) * NCHG + ch) * NP
                 + qb * (WAVES * RF * 32) + wave * (RF * 32);
#pragma unroll
    for (int rf = 0; rf < RF; rf++) {
        float v = __int_as_float(vmini[rf]);
        v = fminf(v, __shfl_xor(v, 32, 64));
        if (lane < 32) pbase[rf * 32 + lane] = v;
    }
}

// ---- reduce: min over DB chunks, weight, sum, atomicAdd ----
__global__ __launch_bounds__(256) void reduce_kernel(
    const float* __restrict__ weights, const float* __restrict__ part,
    float* __restrict__ out)
{
    int tid = threadIdx.x;
    int gid = blockIdx.x * 256 + tid;       // 0 .. 65535
    int dir = gid >> 15;
    int r   = gid & 32767;
    int b   = r >> 13;
    int q   = r & (NP - 1);

    const float* p = part + ((size_t)(dir * BB + b) * NCHG) * NP + q;
    float mn = 1e30f;
#pragma unroll
    for (int i = 0; i < NCHG; i++) mn = fminf(mn, p[(size_t)i * NP]);
    float w = dir ? 1.0f : weights[b * NP + q];
    float v = mn * w * (1.0f / BB);
#pragma unroll
    for (int off = 32; off; off >>= 1) v += __shfl_down(v, off, 64);
    __shared__ float ls[4];
    if ((tid & 63) == 0) ls[tid >> 6] = v;
    __syncthreads();
    if (tid == 0) atomicAdd(out, ls[0] + ls[1] + ls[2] + ls[3]);
}

extern "C" void kernel_launch(void* const* d_in, const int* in_sizes, int n_in,
                              void* d_out, int out_size, void* d_ws, size_t ws_size,
                              hipStream_t stream) {
    const float* src = (const float*)d_in[0];   // (B, N, 3)
    const float* tgt = (const float*)d_in[1];   // (B, M, 3)
    const float* wgt = (const float*)d_in[2];   // (B, N)
    float* out = (float*)d_out;

    float* part = (float*)d_ws;                 // 2 MB: [2][BB][NCHG][NP]

    scan_kernel<<<dim3(QBLOCKS, BB, 2 * NCHG), dim3(256), 0, stream>>>(
        src, tgt, part, out);
    reduce_kernel<<<dim3(256), dim3(256), 0, stream>>>(wgt, part, out);
}

// Round 3
// 75.932 us; speedup vs baseline: 2.3465x; 2.3027x over previous
//
#include <hip/hip_runtime.h>

// Weighted Chamfer, B=4, N=M=8192, D=3, fp32 in/out.
// out = (1/B)*[ sum_b sum_n w*min_m d2 + sum_b sum_m min_n d2 ]
//
// One v_mfma_f32_32x32x16_bf16 yields a 32x32 tile of d2 = s2 + t2 - 2 s.t
// via K-slot packing with split-bf16 compensation (verified r2-r17):
//   A(plain)  half0 {hx,hx,lx,hy,hy,ly,hz,hz} half1 {lz,h2,l2,1,1,0,0,0}
//   B(-2 scl) half0 {nhx,nlx,nhx,nhy,nly,nhy,nhz,nlz} half1 {nhz,1,1,h2,l2,0,0,0}
//   Error ~1e-5 (threshold 5.76). C/D layout: col=lane&31.
// Transposed operands (r8): DB = A staged in LDS, queries = B in registers ->
// per-lane scalar running min. i32-domain min (r13) folds to v_min3_i32.
// Self-packing (r14): no prep kernel; -2*bf16 in int bits ((h^0x8000)+0x80).
// Reg rule (r16/r20/r21): body needs >= ~100-reg budget, launch_bounds(256,4)
// only, AND no source-level modulo scheduling: keeping >=3 f32x16 mfma
// results live across min3 chains trips the allocator into a 64-VGPR spill
// regime (r20: 335 MB scratch, r21: 334 MB scratch, scan 124-127 us).
// Results must be consumed immediately after issue (r19 structure).
// Fence rule (r18): fused finishers falsified; separate reduce launch.
//
// Round 22: r19 structure restored EXACTLY; single change — each rf's
// running min is split into 4 INDEPENDENT accumulator chains (depth 16->4,
// +12 scalar VGPRs only), merged in the epilogue. Theory: the 16-deep
// serial v_min3_i32 chain is dependency-limited (~4 cyc/link = 64 cyc/beat
// while issuing 32) -> VALUBusy 52% with half the cycles idle; splitting
// the chain removes the latency gate without raising mfma-result liveness.

typedef short bf16x8 __attribute__((ext_vector_type(8)));
typedef float f32x16 __attribute__((ext_vector_type(16)));

#define BB 4
#define NP 8192
#define RF 4                     // query-frags per wave (128 queries)
#define WAVES 4                  // 256 threads; 512 queries per block
#define QBLOCKS 16               // 8192 / 512
#define CFRAGS 32                // DB frags per LDS stage (1024 pts, 32 KB)
#define NCHG 8                   // DB chunks (8192 / 1024)

__device__ __forceinline__ int smin3(int a, int b, int c) {
    int m = a < b ? a : b;
    return (m < c) ? m : c;      // folds to v_min3_i32
}
__device__ __forceinline__ int smin2(int a, int b) { return a < b ? a : b; }
__device__ __forceinline__ unsigned short bf16r(float x) {
    unsigned u = __float_as_uint(x);
    unsigned r = u + 0x7FFFu + ((u >> 16) & 1u);
    return (unsigned short)(r >> 16);
}
__device__ __forceinline__ float bf16f(unsigned short h) {
    return __uint_as_float(((unsigned)h) << 16);
}
// -2 * bf16(h), exact in bits (sign flip + exponent+1); h==+-0 -> tiny
// denormal ~1e-38 whose products are << 1e-5 packing error.
__device__ __forceinline__ unsigned short neg2(unsigned short h) {
    return (unsigned short)((h ^ 0x8000u) + 0x0080u);
}

struct Pack {
    unsigned short hx, lx, hy, ly, hz, lz, h2, l2;
};
__device__ __forceinline__ Pack mkpack(float x, float y, float z) {
    Pack p;
    p.hx = bf16r(x); p.lx = bf16r(x - bf16f(p.hx));
    p.hy = bf16r(y); p.ly = bf16r(y - bf16f(p.hy));
    p.hz = bf16r(z); p.lz = bf16r(z - bf16f(p.hz));
    float n2 = x * x + y * y + z * z;
    p.h2 = bf16r(n2); p.l2 = bf16r(n2 - bf16f(p.h2));
    return p;
}

#define ONE 0x3F80u

// ---- scan: self-packing; DB rows from LDS, queries in regs, i32 min3 ----
__global__ __launch_bounds__(256, 4) void scan_kernel(
    const float* __restrict__ src, const float* __restrict__ tgt,
    float* __restrict__ part,   // part[dir][b][ch][query]
    float* __restrict__ out)
{
    __shared__ uint4 ash[CFRAGS * 64];          // 32 KB DB stage (A-packs)
    const int tid = threadIdx.x;
    const int lane = tid & 63, wave = tid >> 6;
    const int qb = blockIdx.x, b = blockIdx.y;
    const int dir = blockIdx.z >> 3, ch = blockIdx.z & (NCHG - 1);

    if (blockIdx.x == 0 && blockIdx.y == 0 && blockIdx.z == 0 && tid == 0)
        out[0] = 0.0f;

    // dir 0: queries = source, DB = target; dir 1 mirrored.
    const float* dbc = (dir ? src : tgt) + ((size_t)b * NP + ch * 1024) * 3;
    const float* qc  = (dir ? tgt : src) + ((size_t)b * NP + qb * (WAVES * RF * 32)) * 3;

    // ---- stage DB chunk: 4 points/thread, pack A-layout into LDS ----
#pragma unroll
    for (int j = 0; j < 4; j++) {
        int i = tid + j * 256;
        float x = dbc[i * 3 + 0], y = dbc[i * 3 + 1], z = dbc[i * 3 + 2];
        Pack p = mkpack(x, y, z);
        uint4 h0, h1;
        h0.x = (unsigned)p.hx | ((unsigned)p.hx << 16);
        h0.y = (unsigned)p.lx | ((unsigned)p.hy << 16);
        h0.z = (unsigned)p.hy | ((unsigned)p.ly << 16);
        h0.w = (unsigned)p.hz | ((unsigned)p.hz << 16);
        h1.x = (unsigned)p.lz | ((unsigned)p.h2 << 16);
        h1.y = (unsigned)p.l2 | (ONE << 16);
        h1.z = ONE;
        h1.w = 0u;
        int f = i >> 5, m = i & 31;
        ash[f * 64 + m]      = h0;
        ash[f * 64 + 32 + m] = h1;
    }

    // ---- pack this lane's query B-frags in registers ----
    const int half = lane >> 5, m = lane & 31;
    bf16x8 qfrag[RF];
#pragma unroll
    for (int rf = 0; rf < RF; rf++) {
        int q = wave * (RF * 32) + rf * 32 + m;
        float x = qc[q * 3 + 0], y = qc[q * 3 + 1], z = qc[q * 3 + 2];
        Pack p = mkpack(x, y, z);
        unsigned short nhx = neg2(p.hx), nlx = neg2(p.lx);
        unsigned short nhy = neg2(p.hy), nly = neg2(p.ly);
        unsigned short nhz = neg2(p.hz), nlz = neg2(p.lz);
        uint4 v;
        if (half == 0) {
            v.x = (unsigned)nhx | ((unsigned)nlx << 16);
            v.y = (unsigned)nhx | ((unsigned)nhy << 16);
            v.z = (unsigned)nly | ((unsigned)nhy << 16);
            v.w = (unsigned)nhz | ((unsigned)nlz << 16);
        } else {
            v.x = (unsigned)nhz | (ONE << 16);
            v.y = ONE | ((unsigned)p.h2 << 16);
            v.z = (unsigned)p.l2;
            v.w = 0u;
        }
        qfrag[rf] = *(bf16x8*)&v;
    }

    // 4 independent min-chains per rf (depth 4 instead of 16); static
    // indexing only (unrolled loops), merged in the epilogue.
    int vm[RF * 4];
#pragma unroll
    for (int k = 0; k < RF * 4; k++) vm[k] = __float_as_int(1e30f);
    f32x16 zero = {};
    __syncthreads();                            // the block's only barrier

    for (int t = 0; t < CFRAGS; t += 2) {
        bf16x8 a0 = *(bf16x8*)&ash[t * 64 + lane];
        bf16x8 a1 = *(bf16x8*)&ash[(t + 1) * 64 + lane];
#pragma unroll
        for (int rf = 0; rf < RF; rf++) {
            f32x16 dA = __builtin_amdgcn_mfma_f32_32x32x16_bf16(a0, qfrag[rf], zero, 0, 0, 0);
            f32x16 dB = __builtin_amdgcn_mfma_f32_32x32x16_bf16(a1, qfrag[rf], zero, 0, 0, 0);
#pragma unroll
            for (int j = 0; j < 4; j++) {       // chain j: depth 4 per pair
                int c = vm[rf * 4 + j];
                c = smin3(__float_as_int(dA[4 * j + 0]), __float_as_int(dA[4 * j + 1]), c);
                c = smin3(__float_as_int(dA[4 * j + 2]), __float_as_int(dA[4 * j + 3]), c);
                c = smin3(__float_as_int(dB[4 * j + 0]), __float_as_int(dB[4 * j + 1]), c);
                c = smin3(__float_as_int(dB[4 * j + 2]), __float_as_int(dB[4 * j + 3]), c);
                vm[rf * 4 + j] = c;
            }
        }
    }

    // finalize: merge 4 chains, then lane^32 holds the other 16 DB rows of
    // the same query column
    float* pbase = part + ((size_t)(dir * BB + b) * NCHG + ch) * NP
                 + qb * (WAVES * RF * 32) + wave * (RF * 32);
#pragma unroll
    for (int rf = 0; rf < RF; rf++) {
        int mm = smin2(smin2(vm[rf * 4 + 0], vm[rf * 4 + 1]),
                       smin2(vm[rf * 4 + 2], vm[rf * 4 + 3]));
        float v = __int_as_float(mm);
        v = fminf(v, __shfl_xor(v, 32, 64));
        if (lane < 32) pbase[rf * 32 + lane] = v;
    }
}

// ---- reduce: min over DB chunks, weight, sum, atomicAdd ----
__global__ __launch_bounds__(256) void reduce_kernel(
    const float* __restrict__ weights, const float* __restrict__ part,
    float* __restrict__ out)
{
    int tid = threadIdx.x;
    int gid = blockIdx.x * 256 + tid;       // 0 .. 65535
    int dir = gid >> 15;
    int r   = gid & 32767;
    int b   = r >> 13;
    int q   = r & (NP - 1);

    const float* p = part + ((size_t)(dir * BB + b) * NCHG) * NP + q;
    float mn = 1e30f;
#pragma unroll
    for (int i = 0; i < NCHG; i++) mn = fminf(mn, p[(size_t)i * NP]);
    float w = dir ? 1.0f : weights[b * NP + q];
    float v = mn * w * (1.0f / BB);
#pragma unroll
    for (int off = 32; off; off >>= 1) v += __shfl_down(v, off, 64);
    __shared__ float ls[4];
    if ((tid & 63) == 0) ls[tid >> 6] = v;
    __syncthreads();
    if (tid == 0) atomicAdd(out, ls[0] + ls[1] + ls[2] + ls[3]);
}

extern "C" void kernel_launch(void* const* d_in, const int* in_sizes, int n_in,
                              void* d_out, int out_size, void* d_ws, size_t ws_size,
                              hipStream_t stream) {
    const float* src = (const float*)d_in[0];   // (B, N, 3)
    const float* tgt = (const float*)d_in[1];   // (B, M, 3)
    const float* wgt = (const float*)d_in[2];   // (B, N)
    float* out = (float*)d_out;

    float* part = (float*)d_ws;                 // 2 MB: [2][BB][NCHG][NP]

    scan_kernel<<<dim3(QBLOCKS, BB, 2 * NCHG), dim3(256), 0, stream>>>(
        src, tgt, part, out);
    reduce_kernel<<<dim3(256), dim3(256), 0, stream>>>(wgt, part, out);
}